// Round 1
// baseline (361.992 us; speedup 1.0000x reference)
//
#include <hip/hip_runtime.h>

// Problem constants
#define Bsz 16384
#define Isz 512
#define Hsz 512
#define Ksz 1024   // I + H
#define N4H 2048   // 4*H

// GEMM tile
#define BM 128
#define BK 64

typedef __bf16 bf16x8 __attribute__((ext_vector_type(8)));
typedef __bf16 bf16x4 __attribute__((ext_vector_type(4)));
typedef float  f32x4  __attribute__((ext_vector_type(4)));

__device__ __forceinline__ void async_copy16(const void* g, void* l) {
    __builtin_amdgcn_global_load_lds(
        (__attribute__((address_space(1))) void*)g,
        (__attribute__((address_space(3))) void*)l,
        16, 0, 0);
}

// ---------------------------------------------------------------------------
// Pack activations: Aq[b][k] = bf16( k<512 ? input[b][k] : h_prev[b][k-512] )
// ---------------------------------------------------------------------------
__global__ void pack_act(const float* __restrict__ x, const float* __restrict__ h,
                         __bf16* __restrict__ Aq) {
    int idx = blockIdx.x * 256 + threadIdx.x;
    int e   = idx << 2;                 // 4 elements per thread
    int row = e >> 10, col = e & 1023;  // col is a multiple of 4, never straddles 512
    const float4 v = (col < Isz)
        ? *(const float4*)(x + (size_t)row * Isz + col)
        : *(const float4*)(h + (size_t)row * Hsz + (col - Isz));
    bf16x4 o = { (__bf16)v.x, (__bf16)v.y, (__bf16)v.z, (__bf16)v.w };
    *(bf16x4*)(Aq + (size_t)e) = o;
}

// ---------------------------------------------------------------------------
// Pack weights with gate-interleaved permutation + fused bias.
// Permuted row p (in [0,2048)): nb=p/128, n=p%128; wn=n>>6, gate=(n>>4)&3,
// c=n&15 -> original row = gate*512 + nb*32 + wn*16 + c.
// This makes each GEMM block's 128 columns = {4 gates} x {32 h}, arranged so
// one wave's 4 column-tiles are the 4 gates of the same 16 h values.
// ---------------------------------------------------------------------------
__global__ void pack_w(const float* __restrict__ Wxh, const float* __restrict__ Whh,
                       const float* __restrict__ bxh, const float* __restrict__ bhh,
                       __bf16* __restrict__ Bq, float* __restrict__ bias) {
    int idx = blockIdx.x * 256 + threadIdx.x;
    int p   = idx >> 8;            // permuted row, 256 k-groups per row
    int k   = (idx & 255) << 2;
    int nb  = p >> 7, n = p & 127;
    int wn  = n >> 6, t = (n >> 4) & 3, c = n & 15;
    int orow = t * Hsz + nb * 32 + wn * 16 + c;
    const float4 v = (k < Isz)
        ? *(const float4*)(Wxh + (size_t)orow * Isz + k)
        : *(const float4*)(Whh + (size_t)orow * Hsz + (k - Isz));
    bf16x4 o = { (__bf16)v.x, (__bf16)v.y, (__bf16)v.z, (__bf16)v.w };
    *(bf16x4*)(Bq + (size_t)p * Ksz + k) = o;
    if ((idx & 255) == 0) bias[p] = bxh[orow] + bhh[orow];
}

// ---------------------------------------------------------------------------
// Fused GEMM + sLSTM epilogue.
// Block: 256 threads = 4 waves in 2x2; each wave owns a 64x64 sub-tile
// (4x4 of 16x16x32 MFMA). Block tile: 128 rows (batch) x 128 cols
// (= 4 gates x 32 h). Grid: (16384/128, 512/32) = (128, 16).
// ---------------------------------------------------------------------------
__global__ __launch_bounds__(256, 2) void slstm_gemm(
    const __bf16* __restrict__ Aq, const __bf16* __restrict__ Bq,
    const float* __restrict__ bias,
    const float* __restrict__ c_prev, const float* __restrict__ m_prev,
    const float* __restrict__ n_prev, float* __restrict__ out) {

    __shared__ __bf16 As[BM * BK];   // 16 KiB
    __shared__ __bf16 Bs[BM * BK];   // 16 KiB

    const int tid  = threadIdx.x;
    const int w    = tid >> 6;
    const int lane = tid & 63;
    const int wm   = w & 1;          // wave row (0..1)
    const int wn   = w >> 1;         // wave col (0..1)
    const int bm   = blockIdx.x;     // batch tile
    const int nb   = blockIdx.y;     // h tile (32 h per block)

    const __bf16* Ag = Aq + (size_t)bm * BM * Ksz;
    const __bf16* Bg = Bq + (size_t)nb * BM * Ksz;   // 128 permuted weight rows

    f32x4 acc[4][4];
    const f32x4 zero = {0.f, 0.f, 0.f, 0.f};
#pragma unroll
    for (int mi = 0; mi < 4; ++mi)
#pragma unroll
        for (int ni = 0; ni < 4; ++ni) acc[mi][ni] = zero;

    // Staging geometry: 16 chunks of 1024 B per tile (8 rows each); wave w
    // owns chunks w*4 .. w*4+3. Lane covers row chunk*8 + (lane>>3),
    // byte offset (lane&7)*16 — matches HW lane*16 LDS scatter exactly.
    const int srow = (lane >> 3);
    const int scol = (lane & 7) * 8;     // in elements

    for (int k0 = 0; k0 < Ksz; k0 += BK) {
        __syncthreads();   // previous iteration's compute done before overwrite
#pragma unroll
        for (int i = 0; i < 4; ++i) {
            const int chunk = w * 4 + i;
            const int row   = chunk * 8 + srow;
            async_copy16(Ag + (size_t)row * Ksz + k0 + scol, (char*)As + chunk * 1024);
            async_copy16(Bg + (size_t)row * Ksz + k0 + scol, (char*)Bs + chunk * 1024);
        }
        __syncthreads();   // implicit vmcnt(0) drain completes the LDS fills

#pragma unroll
        for (int kk = 0; kk < 2; ++kk) {
            bf16x8 af[4], bf[4];
#pragma unroll
            for (int mi = 0; mi < 4; ++mi) {
                const int r = wm * 64 + mi * 16 + (lane & 15);
                af[mi] = *(const bf16x8*)(As + r * BK + kk * 32 + (lane >> 4) * 8);
            }
#pragma unroll
            for (int ni = 0; ni < 4; ++ni) {
                const int r = wn * 64 + ni * 16 + (lane & 15);
                bf[ni] = *(const bf16x8*)(Bs + r * BK + kk * 32 + (lane >> 4) * 8);
            }
#pragma unroll
            for (int mi = 0; mi < 4; ++mi)
#pragma unroll
                for (int ni = 0; ni < 4; ++ni)
                    acc[mi][ni] = __builtin_amdgcn_mfma_f32_16x16x32_bf16(
                        af[mi], bf[ni], acc[mi][ni], 0, 0, 0);
        }
    }

    // ---------------- fused sLSTM epilogue ----------------
    // Lane's h is shared by all 4 column-tiles (ni == gate index).
    const int hidx = nb * 32 + wn * 16 + (lane & 15);
    const int quad = lane >> 4;

    float bsv[4];
#pragma unroll
    for (int ni = 0; ni < 4; ++ni)
        bsv[ni] = bias[nb * 128 + wn * 64 + ni * 16 + (lane & 15)];

    const size_t BH = (size_t)Bsz * Hsz;

#pragma unroll
    for (int mi = 0; mi < 4; ++mi) {
        const int mbase = bm * 128 + wm * 64 + mi * 16 + quad * 4;
#pragma unroll
        for (int r = 0; r < 4; ++r) {
            const int m = mbase + r;
            const size_t off = (size_t)m * Hsz + hidx;
            const float ig = acc[mi][0][r] + bsv[0];
            const float fg = acc[mi][1][r] + bsv[1];
            const float zg = acc[mi][2][r] + bsv[2];
            const float og = acc[mi][3][r] + bsv[3];
            const float cp = c_prev[off];
            const float mp = m_prev[off];
            const float np = n_prev[off];
            const float zt = tanhf(zg);
            const float ot = 1.f / (1.f + expf(-og));
            const float fm = fg + mp;
            const float mt = fmaxf(fm, ig);
            const float it = expf(ig - mt);
            const float ft = expf(fm - mt);
            const float ct = ft * cp + it * zt;
            const float nt = ft * np + it;
            const float ht = ot * (ct / nt);
            out[off]          = ht;
            out[BH + off]     = ct;
            out[2 * BH + off] = mt;
            out[3 * BH + off] = nt;
        }
    }
}

// ---------------------------------------------------------------------------
extern "C" void kernel_launch(void* const* d_in, const int* in_sizes, int n_in,
                              void* d_out, int out_size, void* d_ws, size_t ws_size,
                              hipStream_t stream) {
    const float* input  = (const float*)d_in[0];
    const float* h_prev = (const float*)d_in[1];
    const float* c_prev = (const float*)d_in[2];
    const float* m_prev = (const float*)d_in[3];
    const float* n_prev = (const float*)d_in[4];
    const float* Wxh    = (const float*)d_in[5];
    const float* bxh    = (const float*)d_in[6];
    const float* Whh    = (const float*)d_in[7];
    const float* bhh    = (const float*)d_in[8];
    float* out = (float*)d_out;

    // Workspace layout: Aq (32 MiB bf16) | Bq (4 MiB bf16) | bias (8 KiB f32)
    __bf16* Aq   = (__bf16*)d_ws;
    __bf16* Bq   = (__bf16*)((char*)d_ws + (size_t)Bsz * Ksz * 2);
    float*  bias = (float*)((char*)d_ws + (size_t)Bsz * Ksz * 2 + (size_t)N4H * Ksz * 2);

    pack_act<<<(Bsz * Ksz / 4) / 256, 256, 0, stream>>>(input, h_prev, Aq);
    pack_w<<<(N4H * Ksz / 4) / 256, 256, 0, stream>>>(Wxh, Whh, bxh, bhh, Bq, bias);

    dim3 grid(Bsz / BM, Hsz / 32);
    slstm_gemm<<<grid, 256, 0, stream>>>(Aq, Bq, bias, c_prev, m_prev, n_prev, out);
}

// Round 2
// 344.575 us; speedup vs baseline: 1.0505x; 1.0505x over previous
//
#include <hip/hip_runtime.h>

// Problem constants
#define Bsz 16384
#define Isz 512
#define Hsz 512
#define Ksz 1024   // I + H
#define N4H 2048   // 4*H

// GEMM tile
#define BM 128
#define BK 64

typedef __bf16 bf16x8 __attribute__((ext_vector_type(8)));
typedef __bf16 bf16x4 __attribute__((ext_vector_type(4)));
typedef float  f32x4  __attribute__((ext_vector_type(4)));

__device__ __forceinline__ void async_copy16(const void* g, void* l) {
    __builtin_amdgcn_global_load_lds(
        (__attribute__((address_space(1))) void*)g,
        (__attribute__((address_space(3))) void*)l,
        16, 0, 0);
}

// ---------------------------------------------------------------------------
// Combined pack kernel.
// Blocks [0, 16384): activations  Aq[b][k] = bf16([input|h_prev][b][k])
// Blocks [16384, 18432): weights with gate-interleaved row permutation +
//   fused bias.  Permuted row p: nb=p/128, n=p%128; wn=n>>6, gate=(n>>4)&3,
//   c=n&15 -> original row = gate*512 + nb*32 + wn*16 + c.  This makes each
//   GEMM block's 128 columns = {4 gates} x {32 h}, so one wave's 4 column
//   tiles are the 4 gates of the same 16 h values (register-local epilogue).
// ---------------------------------------------------------------------------
__global__ void pack_all(const float* __restrict__ x, const float* __restrict__ h,
                         const float* __restrict__ Wxh, const float* __restrict__ Whh,
                         const float* __restrict__ bxh, const float* __restrict__ bhh,
                         __bf16* __restrict__ Aq, __bf16* __restrict__ Bq,
                         float* __restrict__ bias) {
    if (blockIdx.x < 16384) {
        int idx = blockIdx.x * 256 + threadIdx.x;
        int e   = idx << 2;                 // 4 elements per thread
        int row = e >> 10, col = e & 1023;  // col multiple of 4, never straddles 512
        const float4 v = (col < Isz)
            ? *(const float4*)(x + (size_t)row * Isz + col)
            : *(const float4*)(h + (size_t)row * Hsz + (col - Isz));
        bf16x4 o = { (__bf16)v.x, (__bf16)v.y, (__bf16)v.z, (__bf16)v.w };
        *(bf16x4*)(Aq + (size_t)e) = o;
    } else {
        int idx = (blockIdx.x - 16384) * 256 + threadIdx.x;
        int p   = idx >> 8;            // permuted row, 256 k-groups per row
        int k   = (idx & 255) << 2;
        int nb  = p >> 7, n = p & 127;
        int wn  = n >> 6, t = (n >> 4) & 3, c = n & 15;
        int orow = t * Hsz + nb * 32 + wn * 16 + c;
        const float4 v = (k < Isz)
            ? *(const float4*)(Wxh + (size_t)orow * Isz + k)
            : *(const float4*)(Whh + (size_t)orow * Hsz + (k - Isz));
        bf16x4 o = { (__bf16)v.x, (__bf16)v.y, (__bf16)v.z, (__bf16)v.w };
        *(bf16x4*)(Bq + (size_t)p * Ksz + k) = o;
        if ((idx & 255) == 0) bias[p] = bxh[orow] + bhh[orow];
    }
}

// ---------------------------------------------------------------------------
// Fused GEMM + sLSTM epilogue.
// Block: 256 threads = 4 waves in 2x2; each wave owns a 64x64 sub-tile
// (4x4 of 16x16x32 MFMA). Block tile: 128 rows (batch) x 128 cols
// (= 4 gates x 32 h). Grid: (16384/128, 512/32) = (128, 16).
//
// LDS layout is XOR-swizzled to kill ds_read_b128 bank conflicts:
// row r's 16-B group g is stored at group position g^(r&7). Staging keeps the
// HW-mandated dest = base + lane*16 and instead permutes each lane's global
// SOURCE group; fragment reads apply p = g ^ (r&7). This spreads each wave64
// ds_read_b128 across all 32 banks (8 dwords/bank = the minimum) instead of
// 16 banks (16/bank) — R1 measured 2.5e7 conflict cycles (~27% of kernel).
// ---------------------------------------------------------------------------
__global__ __launch_bounds__(256, 4) void slstm_gemm(
    const __bf16* __restrict__ Aq, const __bf16* __restrict__ Bq,
    const float* __restrict__ bias,
    const float* __restrict__ c_prev, const float* __restrict__ m_prev,
    const float* __restrict__ n_prev, float* __restrict__ out) {

    __shared__ __bf16 As[BM * BK];   // 16 KiB
    __shared__ __bf16 Bs[BM * BK];   // 16 KiB

    const int tid  = threadIdx.x;
    const int w    = tid >> 6;
    const int lane = tid & 63;
    const int wm   = w & 1;          // wave row (0..1)
    const int wn   = w >> 1;         // wave col (0..1)
    const int bm   = blockIdx.x;     // batch tile
    const int nb   = blockIdx.y;     // h tile (32 h per block)

    const __bf16* Ag = Aq + (size_t)bm * BM * Ksz;
    const __bf16* Bg = Bq + (size_t)nb * BM * Ksz;   // 128 permuted weight rows

    f32x4 acc[4][4];
    const f32x4 zero = {0.f, 0.f, 0.f, 0.f};
#pragma unroll
    for (int mi = 0; mi < 4; ++mi)
#pragma unroll
        for (int ni = 0; ni < 4; ++ni) acc[mi][ni] = zero;

    // Staging geometry: 16 chunks of 1024 B per tile (8 rows each); wave w
    // owns chunks w*4 .. w*4+3. Lane L covers row chunk*8 + (L>>3); its LDS
    // slot is within-row group position L&7, which (swizzled) must hold
    // global group (L&7) ^ ((L>>3)&7).
    const int srow = (lane >> 3);
    const int scol = ((lane & 7) ^ srow) * 8;     // swizzled source, in elements

    for (int k0 = 0; k0 < Ksz; k0 += BK) {
        __syncthreads();   // previous iteration's compute done before overwrite
#pragma unroll
        for (int i = 0; i < 4; ++i) {
            const int chunk = w * 4 + i;
            const int row   = chunk * 8 + srow;
            async_copy16(Ag + (size_t)row * Ksz + k0 + scol, (char*)As + chunk * 1024);
            async_copy16(Bg + (size_t)row * Ksz + k0 + scol, (char*)Bs + chunk * 1024);
        }
        __syncthreads();   // implicit vmcnt(0) drain completes the LDS fills

#pragma unroll
        for (int kk = 0; kk < 2; ++kk) {
            bf16x8 af[4], bf[4];
#pragma unroll
            for (int mi = 0; mi < 4; ++mi) {
                const int r = wm * 64 + mi * 16 + (lane & 15);
                const int p = (kk * 4 + (lane >> 4)) ^ (r & 7);
                af[mi] = *(const bf16x8*)(As + r * BK + p * 8);
            }
#pragma unroll
            for (int ni = 0; ni < 4; ++ni) {
                const int r = wn * 64 + ni * 16 + (lane & 15);
                const int p = (kk * 4 + (lane >> 4)) ^ (r & 7);
                bf[ni] = *(const bf16x8*)(Bs + r * BK + p * 8);
            }
#pragma unroll
            for (int mi = 0; mi < 4; ++mi)
#pragma unroll
                for (int ni = 0; ni < 4; ++ni)
                    acc[mi][ni] = __builtin_amdgcn_mfma_f32_16x16x32_bf16(
                        af[mi], bf[ni], acc[mi][ni], 0, 0, 0);
        }
    }

    // ---------------- fused sLSTM epilogue ----------------
    // Lane's h is shared by all 4 column-tiles (ni == gate index).
    const int hidx = nb * 32 + wn * 16 + (lane & 15);
    const int quad = lane >> 4;

    float bsv[4];
#pragma unroll
    for (int ni = 0; ni < 4; ++ni)
        bsv[ni] = bias[nb * 128 + wn * 64 + ni * 16 + (lane & 15)];

    const size_t BH = (size_t)Bsz * Hsz;

#pragma unroll
    for (int mi = 0; mi < 4; ++mi) {
        const int mbase = bm * 128 + wm * 64 + mi * 16 + quad * 4;
#pragma unroll
        for (int r = 0; r < 4; ++r) {
            const int m = mbase + r;
            const size_t off = (size_t)m * Hsz + hidx;
            const float ig = acc[mi][0][r] + bsv[0];
            const float fg = acc[mi][1][r] + bsv[1];
            const float zg = acc[mi][2][r] + bsv[2];
            const float og = acc[mi][3][r] + bsv[3];
            const float cp = c_prev[off];
            const float mp = m_prev[off];
            const float np = n_prev[off];
            const float zt = tanhf(zg);
            const float ot = 1.f / (1.f + expf(-og));
            const float fm = fg + mp;
            const float mt = fmaxf(fm, ig);
            const float it = expf(ig - mt);
            const float ft = expf(fm - mt);
            const float ct = ft * cp + it * zt;
            const float nt = ft * np + it;
            const float ht = ot * (ct / nt);
            out[off]          = ht;
            out[BH + off]     = ct;
            out[2 * BH + off] = mt;
            out[3 * BH + off] = nt;
        }
    }
}

// ---------------------------------------------------------------------------
extern "C" void kernel_launch(void* const* d_in, const int* in_sizes, int n_in,
                              void* d_out, int out_size, void* d_ws, size_t ws_size,
                              hipStream_t stream) {
    const float* input  = (const float*)d_in[0];
    const float* h_prev = (const float*)d_in[1];
    const float* c_prev = (const float*)d_in[2];
    const float* m_prev = (const float*)d_in[3];
    const float* n_prev = (const float*)d_in[4];
    const float* Wxh    = (const float*)d_in[5];
    const float* bxh    = (const float*)d_in[6];
    const float* Whh    = (const float*)d_in[7];
    const float* bhh    = (const float*)d_in[8];
    float* out = (float*)d_out;

    // Workspace layout: Aq (32 MiB bf16) | Bq (4 MiB bf16) | bias (8 KiB f32)
    __bf16* Aq   = (__bf16*)d_ws;
    __bf16* Bq   = (__bf16*)((char*)d_ws + (size_t)Bsz * Ksz * 2);
    float*  bias = (float*)((char*)d_ws + (size_t)Bsz * Ksz * 2 + (size_t)N4H * Ksz * 2);

    // 16384 activation blocks + 2048 weight blocks in one launch
    pack_all<<<16384 + 2048, 256, 0, stream>>>(input, h_prev, Wxh, Whh, bxh, bhh,
                                               Aq, Bq, bias);

    dim3 grid(Bsz / BM, Hsz / 32);
    slstm_gemm<<<grid, 256, 0, stream>>>(Aq, Bq, bias, c_prev, m_prev, n_prev, out);
}